// Round 1
// 175.954 us; speedup vs baseline: 1.1278x; 1.1278x over previous
//
#include <hip/hip_runtime.h>
#include <hip/hip_bf16.h>

#define BB   2
#define NN   128
#define SS   4
#define DGG  8
#define CIN  4
#define COUT 8
#define HH   32

typedef __attribute__((ext_vector_type(4))) float          fvec4;
typedef __attribute__((ext_vector_type(4))) unsigned short usvec4;
typedef __attribute__((ext_vector_type(8))) unsigned short usvec8;
typedef __attribute__((ext_vector_type(2))) __fp16         half2v;
typedef __attribute__((ext_vector_type(8))) __fp16         f16x8;
typedef __attribute__((ext_vector_type(4))) float          f32x4;
typedef __attribute__((ext_vector_type(4))) unsigned int   uvec4;

__device__ __forceinline__ float bf2f(unsigned short u) {
    return __uint_as_float(((unsigned int)u) << 16);
}
__device__ __forceinline__ float silu_f(float x) {
    float e = __builtin_amdgcn_exp2f(x * -1.44269504f);
    return x * __builtin_amdgcn_rcpf(1.0f + e);
}
__device__ __forceinline__ float exp_f(float x) {
    return __builtin_amdgcn_exp2f(x * 1.44269504f);
}

__device__ __forceinline__ half2v upk(unsigned int u) {
    union { unsigned int u; half2v h; } x; x.u = u; return x.h;
}
__device__ __forceinline__ unsigned int pk2u(float a, float b) {
#if __has_builtin(__builtin_amdgcn_cvt_pkrtz)
    half2v h = __builtin_amdgcn_cvt_pkrtz(a, b);
#else
    half2v h; h[0] = (__fp16)a; h[1] = (__fp16)b;
#endif
    union { half2v h; unsigned int u; } x; x.h = h; return x.u;
}
union FU { uvec4 u; f16x8 h; };
__device__ __forceinline__ f16x8 mk_frag(unsigned a, unsigned b, unsigned c, unsigned d) {
    FU x; x.u = (uvec4){a, b, c, d}; return x.h;
}

__device__ __forceinline__ float loadS(const void* p, int idx, int fmode) {
    return fmode ? bf2f(((const unsigned short*)p)[idx])
                 : ((const float*)p)[idx];
}
__device__ __forceinline__ void load8(const void* p, int base, int fmode, float* dst) {
    if (fmode) {
        usvec8 v = *(const usvec8*)((const unsigned short*)p + base);
#pragma unroll
        for (int d = 0; d < 8; ++d) dst[d] = bf2f(v[d]);
    } else {
        fvec4 a = *(const fvec4*)((const float*)p + base);
        fvec4 b = *(const fvec4*)((const float*)p + base + 4);
        dst[0] = a[0]; dst[1] = a[1]; dst[2] = a[2]; dst[3] = a[3];
        dst[4] = b[0]; dst[5] = b[1]; dst[6] = b[2]; dst[7] = b[3];
    }
}
// 8 consecutive weights -> packed u32x4 (f16 pairs), element r = k offset r
__device__ __forceinline__ uvec4 load_row8u(const void* p, int eoff, int fmode) {
    uvec4 u;
    if (fmode) {
        usvec8 v = *(const usvec8*)((const unsigned short*)p + eoff);
#pragma unroll
        for (int q = 0; q < 4; ++q) u[q] = pk2u(bf2f(v[2 * q]), bf2f(v[2 * q + 1]));
    } else {
        fvec4 a = *(const fvec4*)((const float*)p + eoff);
        fvec4 b = *(const fvec4*)((const float*)p + eoff + 4);
        u[0] = pk2u(a[0], a[1]); u[1] = pk2u(a[2], a[3]);
        u[2] = pk2u(b[0], b[1]); u[3] = pk2u(b[2], b[3]);
    }
    return u;
}
__device__ __forceinline__ f16x8 load_row8(const void* p, int eoff, int fmode) {
    uvec4 u = load_row8u(p, eoff, fmode);
    return mk_frag(u[0], u[1], u[2], u[3]);
}
__device__ __forceinline__ int load_mask(const void* p, int idx, int mmode) {
    if (mmode == 0) return ((const int*)p)[idx] != 0;
    if (mmode == 1) return ((const unsigned short*)p)[idx] != 0;
    if (mmode == 2) return ((const unsigned char*)p)[idx] != 0;
    return ((const unsigned int*)p)[idx] != 0;
}
__device__ __forceinline__ void stage_pk(unsigned int* dst, const void* src,
                                         int pairs, int fmode, int tid) {
    if (fmode) {
        const unsigned short* s = (const unsigned short*)src;
        for (int x = tid; x < pairs; x += 256)
            dst[x] = pk2u(bf2f(s[2 * x]), bf2f(s[2 * x + 1]));
    } else {
        const float* s = (const float*)src;
        for (int x = tid; x < pairs; x += 256)
            dst[x] = pk2u(s[2 * x], s[2 * x + 1]);
    }
}
__device__ __forceinline__ void copy_arr(float* sm, const void* src, int off,
                                         int cnt, int fmode, int tid) {
    if (fmode) {
        const unsigned short* s = (const unsigned short*)src;
        for (int x = tid; x < cnt; x += 256) sm[off + x] = bf2f(s[x]);
    } else {
        const float* s = (const float*)src;
        for (int x = tid; x < cnt; x += 256) sm[off + x] = s[x];
    }
}
// modes: [0]=float dtype (0=f32,1=bf16), [1]=mask dtype (0=i32,1=bf16,2=u8,3=f32)
__device__ __forceinline__ void detect_inline(const void* g_mask, const void* g_coset,
                                              int tid, int* smi, int slot) {
    if (tid < 64) {
        const unsigned short* cu = (const unsigned short*)g_coset;
        unsigned short v = cu[2 * tid];
        int e = (v >> 7) & 0xFF;
        int hits = __popcll(__ballot(e >= 110 && e <= 135));
        int fmode_ = (hits > 32) ? 1 : 0;
        const unsigned short* mu = (const unsigned short*)g_mask;
        int evenBF = 0, any3 = 0, anyByte = 0;
        for (int r = 0; r < 8; ++r) {
            int idx = tid + r * 64;
            unsigned short m = mu[idx];
            if (m == 0x3F80) { any3 = 1; if (!(idx & 1)) evenBF = 1; }
            if (m == 0x0101 || m == 0x0100) anyByte = 1;
        }
        evenBF  = (__ballot(evenBF)  != 0ull);
        any3    = (__ballot(any3)    != 0ull);
        anyByte = (__ballot(anyByte) != 0ull);
        if (tid == 0) {
            smi[slot]     = fmode_;
            smi[slot + 1] = evenBF ? 1 : (any3 ? 3 : (anyByte ? 2 : 0));
        }
    }
}

// LDS layout (u32 units) — gW1 staging removed (W1g now rides in MFMA A-frags
// straight from global), layout compacted.
#define UG_G    0      // 2048: pairwise_g slice for (bn,s1), packed f16 [pos][4]
#define F_FA    2048   // 2048 f32: coset b-slice [pos2=n*4+s][ci]
#define U_MASK  4096   // 512: key mask per pos (0/1)
#define U_YW1   4608   // 128 pairs (w0,w1) per (ci,j1)
#define F_YB1   4736   // 128
#define F_YB2   4864   // 128
#define F_YW3   4992   // 128
#define F_GB1   5120   // 128
#define F_GB2   5248   // 128
#define F_GW3   5376   // 128
#define F_YB3   5504   // 4
#define F_GB3   5508   // 4
#define F_RED   5512   // 32: [wave][ci][N,D]
#define F_MODE  5544   // 2
#define U_TOTAL 5546   // ~22.2 KB

// One block per (bn, s1); 256 threads = 4 waves; wave handles 8 position-
// tiles of 16 (pos = n2*4+s2 in [0,512)).
//
// kg L1 now runs on the MFMA pipe (was 32 v_dot2 + 8 ds_read_b128 per iter):
// two 16x16x32 MFMAs whose A-fragments hold ROW-PERMUTED W1g —
//   MFMA#A row m = hidden 8*(m>>2)+(m&3), MFMA#B row m = that +4 —
// so lane (quad,col) receives exactly hidden {8*quad .. 8*quad+7} of its
// position, i.e. the L2 B-fragment layout DIRECTLY (no cross-lane fixup).
// K is padded 8->32 by zeroing the A-frags for quads 1-3 (loop-invariant);
// the per-iteration B-frag is the raw gq for ALL quads (garbage k>=8 rows
// multiply A=0).  All biases (b1g, b2y, b2g) are folded into MFMA C operands,
// which also forces those constants into registers instead of per-iter LDS
// re-reads (previous binary sat at VGPR=64 => compiler re-read LDS per iter).
//
// ky L1 stays per-lane scalar (2-input, 8 fma) directly in B-layout.
// L2 on v_mfma_f32_16x16x32_f16 (C/D: row=quad*4+reg, col=lane&15 —
// HW-verified mapping).  L3 = per-lane fma + shfl_xor(16,32).
// Block owns the whole (n2,s2) softmax reduction -> writes its 8 outputs
// directly (no workspace, no finalize launch).
// NOTE: MFMA calls guarded by __HIP_DEVICE_COMPILE__ — the host parsing pass
// doesn't know amdgcn builtins.
__global__ __launch_bounds__(256, 4) void emha_mfma(
    const void* __restrict__ g_pw, const void* __restrict__ g_coset,
    const void* __restrict__ g_mask,
    const void* yW1, const void* yb1, const void* yW2, const void* yb2,
    const void* yW3, const void* yb3,
    const void* gW1, const void* gb1, const void* gW2, const void* gb2,
    const void* gW3, const void* gb3,
    const void* wout, void* outp)
{
    __shared__ __align__(16) unsigned int smu[U_TOTAL];
    float* smf = (float*)smu;
    int*   smi = (int*)smu;
    const int tid = threadIdx.x;

    detect_inline(g_mask, g_coset, tid, smi, F_MODE);
    __syncthreads();
    const int fmode = smi[F_MODE];
    const int mmode = smi[F_MODE + 1];
    __syncthreads();

    const int bn = blockIdx.x >> 2;   // b*128 + n1
    const int s1 = blockIdx.x & 3;
    const int b  = bn >> 7;
    const int n1 = bn & 127;

    // ---- stage pairwise_g slice (pos = n2*4+s2), packed f16 ----
#pragma unroll
    for (int it = 0; it < 2; ++it) {
        const int pos = tid + it * 256;
        const int n2 = pos >> 2, s2 = pos & 3;
        float g8[8];
        load8(g_pw, (((bn * NN + n2) * SS + s1) * SS + s2) * DGG, fmode, g8);
#pragma unroll
        for (int q = 0; q < 4; ++q)
            smu[UG_G + pos * 4 + q] = pk2u(g8[2 * q], g8[2 * q + 1]);
    }
    // ---- stage coset b-slice (f32) and key mask ----
    for (int x = tid; x < 2048; x += 256)
        smf[F_FA + x] = loadS(g_coset, b * 2048 + x, fmode);
    for (int x = tid; x < 512; x += 256)
        smu[U_MASK + x] = (unsigned)load_mask(g_mask, b * 512 + x, mmode);
    // ---- stage ky W1 (packed pairs) + biases/w3 (f32) ----
    stage_pk(&smu[U_YW1], yW1, 128, fmode, tid);
    copy_arr(smf, yb1, F_YB1, 128, fmode, tid);
    copy_arr(smf, yb2, F_YB2, 128, fmode, tid);
    copy_arr(smf, yW3, F_YW3, 128, fmode, tid);
    copy_arr(smf, gb1, F_GB1, 128, fmode, tid);
    copy_arr(smf, gb2, F_GB2, 128, fmode, tid);
    copy_arr(smf, gW3, F_GW3, 128, fmode, tid);
    copy_arr(smf, yb3, F_YB3, 4, fmode, tid);
    copy_arr(smf, gb3, F_GB3, 4, fmode, tid);
    __syncthreads();

    const int lane = tid & 63;
    const int wave = tid >> 6;
    const int quad = lane >> 4;
    const int col  = lane & 15;
    const int qpos = n1 * 4 + s1;     // query index in b-slice

    float accN[4] = {0.f, 0.f, 0.f, 0.f};
    float accD[4] = {0.f, 0.f, 0.f, 0.f};

#pragma unroll
    for (int ci = 0; ci < CIN; ++ci) {
        const float fb = smf[F_FA + qpos * 4 + ci];
        // ky L1 constants for this lane's 8 j1 rows (j1 = quad*8 + jj)
        float w0f[8], cc[8];
        {
            uvec4 pa = *(const uvec4*)&smu[U_YW1 + ci * 32 + quad * 8];
            uvec4 pb = *(const uvec4*)&smu[U_YW1 + ci * 32 + quad * 8 + 4];
            fvec4 ba = *(const fvec4*)&smf[F_YB1 + ci * 32 + quad * 8];
            fvec4 bb = *(const fvec4*)&smf[F_YB1 + ci * 32 + quad * 8 + 4];
#pragma unroll
            for (int jj = 0; jj < 4; ++jj) {
                half2v w = upk(pa[jj]);
                w0f[jj] = (float)w[0];
                cc[jj]  = (float)w[1] * fb + ba[jj];
            }
#pragma unroll
            for (int jj = 0; jj < 4; ++jj) {
                half2v w = upk(pb[jj]);
                w0f[4 + jj] = (float)w[0];
                cc[4 + jj]  = (float)w[1] * fb + bb[jj];
            }
        }
        // W2 A-fragments: A[m=col(+16)][k=quad*8..+7], direct from global
        const f16x8 Ay0 = load_row8(yW2, ci * 1024 + col * 32 + quad * 8, fmode);
        const f16x8 Ay1 = load_row8(yW2, ci * 1024 + (col + 16) * 32 + quad * 8, fmode);
        const f16x8 Ag0 = load_row8(gW2, ci * 1024 + col * 32 + quad * 8, fmode);
        const f16x8 Ag1 = load_row8(gW2, ci * 1024 + (col + 16) * 32 + quad * 8, fmode);
        // kg L1 A-fragments, row-permuted: #A row m -> hidden 8*(m>>2)+(m&3),
        // #B -> +4.  K padded 8->32: quads 1-3 supply zeros (loop-invariant).
        const int hA = ((col >> 2) << 3) + (col & 3);
        uvec4 ua = load_row8u(gW1, ci * 256 + hA * 8, fmode);
        uvec4 ub = load_row8u(gW1, ci * 256 + hA * 8 + 32, fmode);
        if (quad != 0) { ua = (uvec4){0, 0, 0, 0}; ub = (uvec4){0, 0, 0, 0}; }
        const f16x8 GA = mk_frag(ua[0], ua[1], ua[2], ua[3]);
        const f16x8 GB = mk_frag(ub[0], ub[1], ub[2], ub[3]);
        // bias C-operands: L1 kg (b1g rows 8q+r / 8q+4+r), L2 (b2 rows q*4+r)
        const fvec4 cGA = *(const fvec4*)&smf[F_GB1 + ci * 32 + quad * 8];
        const fvec4 cGB = *(const fvec4*)&smf[F_GB1 + ci * 32 + quad * 8 + 4];
        const fvec4 cY0 = *(const fvec4*)&smf[F_YB2 + ci * 32 + quad * 4];
        const fvec4 cY1 = *(const fvec4*)&smf[F_YB2 + ci * 32 + 16 + quad * 4];
        const fvec4 cG0 = *(const fvec4*)&smf[F_GB2 + ci * 32 + quad * 4];
        const fvec4 cG1 = *(const fvec4*)&smf[F_GB2 + ci * 32 + 16 + quad * 4];
        const fvec4 w3y0 = *(const fvec4*)&smf[F_YW3 + ci * 32 + quad * 4];
        const fvec4 w3y1 = *(const fvec4*)&smf[F_YW3 + ci * 32 + 16 + quad * 4];
        const fvec4 w3g0 = *(const fvec4*)&smf[F_GW3 + ci * 32 + quad * 4];
        const fvec4 w3g1 = *(const fvec4*)&smf[F_GW3 + ci * 32 + 16 + quad * 4];
        const float b3y = smf[F_YB3 + ci];
        const float b3g = smf[F_GB3 + ci];

#pragma unroll 1
        for (int t = 0; t < 8; ++t) {
            const int pos = (wave * 8 + t) * 16 + col;
            const float fap = smf[F_FA + pos * 4 + ci];
            const unsigned km = smu[U_MASK + pos];
            const uvec4 gq = *(const uvec4*)&smu[UG_G + pos * 4];
            // L1 kg B-frag: raw gq in ALL quads; k>=8 rows killed by GA/GB=0
            const f16x8 Bg1 = mk_frag(gq[0], gq[1], gq[2], gq[3]);

            // ky L1 -> B-frag (B[k=quad*8+j][n=col])
            unsigned by0 = pk2u(silu_f(w0f[0] * fap + cc[0]), silu_f(w0f[1] * fap + cc[1]));
            unsigned by1 = pk2u(silu_f(w0f[2] * fap + cc[2]), silu_f(w0f[3] * fap + cc[3]));
            unsigned by2 = pk2u(silu_f(w0f[4] * fap + cc[4]), silu_f(w0f[5] * fap + cc[5]));
            unsigned by3 = pk2u(silu_f(w0f[6] * fap + cc[6]), silu_f(w0f[7] * fap + cc[7]));
            const f16x8 By = mk_frag(by0, by1, by2, by3);

            f32x4 dA, dB, dy0, dy1, dg0, dg1;
#if defined(__HIP_DEVICE_COMPILE__)
            // kg L1 on the matrix pipe; bias pre-loaded in C
            dA = __builtin_amdgcn_mfma_f32_16x16x32_f16(GA, Bg1, cGA, 0, 0, 0);
            dB = __builtin_amdgcn_mfma_f32_16x16x32_f16(GB, Bg1, cGB, 0, 0, 0);
#else
            dA = cGA; dB = cGB;  // host parse only
#endif
            // silu + pack: dA[r] = hidden 8q+r, dB[r] = hidden 8q+4+r  ->
            // exactly B-frag element order j = 0..7 for the L2 MFMA
            unsigned bg0 = pk2u(silu_f(dA[0]), silu_f(dA[1]));
            unsigned bg1 = pk2u(silu_f(dA[2]), silu_f(dA[3]));
            unsigned bg2 = pk2u(silu_f(dB[0]), silu_f(dB[1]));
            unsigned bg3 = pk2u(silu_f(dB[2]), silu_f(dB[3]));
            const f16x8 Bg = mk_frag(bg0, bg1, bg2, bg3);

#if defined(__HIP_DEVICE_COMPILE__)
            dy0 = __builtin_amdgcn_mfma_f32_16x16x32_f16(Ay0, By, cY0, 0, 0, 0);
            dy1 = __builtin_amdgcn_mfma_f32_16x16x32_f16(Ay1, By, cY1, 0, 0, 0);
            dg0 = __builtin_amdgcn_mfma_f32_16x16x32_f16(Ag0, Bg, cG0, 0, 0, 0);
            dg1 = __builtin_amdgcn_mfma_f32_16x16x32_f16(Ag1, Bg, cG1, 0, 0, 0);
#else
            dy0 = cY0; dy1 = cY1; dg0 = cG0; dg1 = cG1;  // host parse only
#endif
            // L3: lane holds rows j2 = quad*4+r (+16 for tile 1), col = pos;
            // b2 already added via MFMA C
            float a3y = 0.f, a3g = 0.f;
#pragma unroll
            for (int r = 0; r < 4; ++r) {
                a3y += w3y0[r] * silu_f(dy0[r]);
                a3y += w3y1[r] * silu_f(dy1[r]);
                a3g += w3g0[r] * silu_f(dg0[r]);
                a3g += w3g1[r] * silu_f(dg1[r]);
            }
            a3y += __shfl_xor(a3y, 16); a3y += __shfl_xor(a3y, 32);
            a3g += __shfl_xor(a3g, 16); a3g += __shfl_xor(a3g, 32);

            const float kyv = silu_f(a3y + b3y);
            const float kgv = silu_f(a3g + b3g);
            const float e = km ? exp_f(kyv + kgv) : 0.f;
            accD[ci] += e;
            accN[ci] += e * fap;
        }
    }

    // reduce across the 16 positions (lane bits 0-3; quads hold identical
    // copies after the xor-16/32 reduction)
#pragma unroll
    for (int ci = 0; ci < CIN; ++ci) {
        accN[ci] += __shfl_xor(accN[ci], 1);  accD[ci] += __shfl_xor(accD[ci], 1);
        accN[ci] += __shfl_xor(accN[ci], 2);  accD[ci] += __shfl_xor(accD[ci], 2);
        accN[ci] += __shfl_xor(accN[ci], 4);  accD[ci] += __shfl_xor(accD[ci], 4);
        accN[ci] += __shfl_xor(accN[ci], 8);  accD[ci] += __shfl_xor(accD[ci], 8);
    }
    if (lane == 0) {
#pragma unroll
        for (int ci = 0; ci < CIN; ++ci) {
            smf[F_RED + (wave * 4 + ci) * 2 + 0] = accN[ci];
            smf[F_RED + (wave * 4 + ci) * 2 + 1] = accD[ci];
        }
    }
    __syncthreads();

    if (tid < COUT) {
        const int o = tid;
        const unsigned m1 = smu[U_MASK + qpos];
        float acc = 0.f;
#pragma unroll
        for (int ci = 0; ci < CIN; ++ci) {
            float N = 0.f, D = 0.f;
#pragma unroll
            for (int w = 0; w < 4; ++w) {
                N += smf[F_RED + (w * 4 + ci) * 2 + 0];
                D += smf[F_RED + (w * 4 + ci) * 2 + 1];
            }
            const float fbv = smf[F_FA + qpos * 4 + ci];
            const float cf = m1 ? (fbv + N / D) : 0.f;
            acc += cf * loadS(wout, o * CIN + ci, fmode);
        }
        const int oidx = (bn * SS + s1) * COUT + o;
        if (fmode) ((__hip_bfloat16*)outp)[oidx] = __float2bfloat16(acc);
        else       ((float*)outp)[oidx] = acc;
    }
}

extern "C" void kernel_launch(void* const* d_in, const int* in_sizes, int n_in,
                              void* d_out, int out_size, void* d_ws, size_t ws_size,
                              hipStream_t stream) {
    emha_mfma<<<BB * NN * SS, 256, 0, stream>>>(
        d_in[0], d_in[1], d_in[2],
        d_in[3], d_in[4], d_in[5], d_in[6], d_in[7], d_in[8],
        d_in[9], d_in[10], d_in[11], d_in[12], d_in[13], d_in[14],
        d_in[15], d_out);
}

// Round 3
// 168.780 us; speedup vs baseline: 1.1758x; 1.0425x over previous
//
#include <hip/hip_runtime.h>
#include <hip/hip_bf16.h>

#define BB   2
#define NN   128
#define SS   4
#define DGG  8
#define CIN  4
#define COUT 8
#define HH   32

typedef __attribute__((ext_vector_type(4))) float          fvec4;
typedef __attribute__((ext_vector_type(4))) unsigned short usvec4;
typedef __attribute__((ext_vector_type(8))) unsigned short usvec8;
typedef __attribute__((ext_vector_type(2))) __fp16         half2v;
typedef __attribute__((ext_vector_type(8))) __fp16         f16x8;
typedef __attribute__((ext_vector_type(4))) float          f32x4;
typedef __attribute__((ext_vector_type(4))) unsigned int   uvec4;

__device__ __forceinline__ float bf2f(unsigned short u) {
    return __uint_as_float(((unsigned int)u) << 16);
}
__device__ __forceinline__ float silu_f(float x) {
    float e = __builtin_amdgcn_exp2f(x * -1.44269504f);
    return x * __builtin_amdgcn_rcpf(1.0f + e);
}
__device__ __forceinline__ float exp_f(float x) {
    return __builtin_amdgcn_exp2f(x * 1.44269504f);
}

__device__ __forceinline__ unsigned int pk2u(float a, float b) {
#if __has_builtin(__builtin_amdgcn_cvt_pkrtz)
    half2v h = __builtin_amdgcn_cvt_pkrtz(a, b);
#else
    half2v h; h[0] = (__fp16)a; h[1] = (__fp16)b;
#endif
    union { half2v h; unsigned int u; } x; x.h = h; return x.u;
}
union FU { uvec4 u; f16x8 h; };
__device__ __forceinline__ f16x8 mk_frag(unsigned a, unsigned b, unsigned c, unsigned d) {
    FU x; x.u = (uvec4){a, b, c, d}; return x.h;
}
__device__ __forceinline__ f16x8 mk_fragv(uvec4 u) {
    FU x; x.u = u; return x.h;
}
// silu + pack two f32x4 MFMA outputs into one B-fragment (j = 0..7)
__device__ __forceinline__ f16x8 silu_frag(f32x4 a, f32x4 b) {
    return mk_frag(pk2u(silu_f(a[0]), silu_f(a[1])),
                   pk2u(silu_f(a[2]), silu_f(a[3])),
                   pk2u(silu_f(b[0]), silu_f(b[1])),
                   pk2u(silu_f(b[2]), silu_f(b[3])));
}

__device__ __forceinline__ float loadS(const void* p, int idx, int fmode) {
    return fmode ? bf2f(((const unsigned short*)p)[idx])
                 : ((const float*)p)[idx];
}
__device__ __forceinline__ void load8(const void* p, int base, int fmode, float* dst) {
    if (fmode) {
        usvec8 v = *(const usvec8*)((const unsigned short*)p + base);
#pragma unroll
        for (int d = 0; d < 8; ++d) dst[d] = bf2f(v[d]);
    } else {
        fvec4 a = *(const fvec4*)((const float*)p + base);
        fvec4 b = *(const fvec4*)((const float*)p + base + 4);
        dst[0] = a[0]; dst[1] = a[1]; dst[2] = a[2]; dst[3] = a[3];
        dst[4] = b[0]; dst[5] = b[1]; dst[6] = b[2]; dst[7] = b[3];
    }
}
__device__ __forceinline__ int load_mask(const void* p, int idx, int mmode) {
    if (mmode == 0) return ((const int*)p)[idx] != 0;
    if (mmode == 1) return ((const unsigned short*)p)[idx] != 0;
    if (mmode == 2) return ((const unsigned char*)p)[idx] != 0;
    return ((const unsigned int*)p)[idx] != 0;
}
__device__ __forceinline__ void stage_pk(unsigned int* dst, const void* src,
                                         int pairs, int fmode, int tid) {
    if (fmode) {
        const unsigned short* s = (const unsigned short*)src;
        for (int x = tid; x < pairs; x += 256)
            dst[x] = pk2u(bf2f(s[2 * x]), bf2f(s[2 * x + 1]));
    } else {
        const float* s = (const float*)src;
        for (int x = tid; x < pairs; x += 256)
            dst[x] = pk2u(s[2 * x], s[2 * x + 1]);
    }
}
__device__ __forceinline__ void copy_arr(float* sm, const void* src, int off,
                                         int cnt, int fmode, int tid) {
    if (fmode) {
        const unsigned short* s = (const unsigned short*)src;
        for (int x = tid; x < cnt; x += 256) sm[off + x] = bf2f(s[x]);
    } else {
        const float* s = (const float*)src;
        for (int x = tid; x < cnt; x += 256) sm[off + x] = s[x];
    }
}
// modes: [0]=float dtype (0=f32,1=bf16), [1]=mask dtype (0=i32,1=bf16,2=u8,3=f32)
__device__ __forceinline__ void detect_inline(const void* g_mask, const void* g_coset,
                                              int tid, int* smi, int slot) {
    if (tid < 64) {
        const unsigned short* cu = (const unsigned short*)g_coset;
        unsigned short v = cu[2 * tid];
        int e = (v >> 7) & 0xFF;
        int hits = __popcll(__ballot(e >= 110 && e <= 135));
        int fmode_ = (hits > 32) ? 1 : 0;
        const unsigned short* mu = (const unsigned short*)g_mask;
        int evenBF = 0, any3 = 0, anyByte = 0;
        for (int r = 0; r < 8; ++r) {
            int idx = tid + r * 64;
            unsigned short m = mu[idx];
            if (m == 0x3F80) { any3 = 1; if (!(idx & 1)) evenBF = 1; }
            if (m == 0x0101 || m == 0x0100) anyByte = 1;
        }
        evenBF  = (__ballot(evenBF)  != 0ull);
        any3    = (__ballot(any3)    != 0ull);
        anyByte = (__ballot(anyByte) != 0ull);
        if (tid == 0) {
            smi[slot]     = fmode_;
            smi[slot + 1] = evenBF ? 1 : (any3 ? 3 : (anyByte ? 2 : 0));
        }
    }
}

// LDS layout (u32 units) — ALL weights staged pre-packed as f16 pairs in
// MFMA-fragment-friendly natural order, so any rematerialized fragment is a
// single ds_read_b128 (round-1 binary sat at VGPR=64 and re-fetched W2 frags
// from GLOBAL + reconverted per t-iteration: ~600 VALU instrs/iter observed
// vs ~200 ideal).
#define UG_G    0      // 2048: pairwise_g slice for (bn,s1), packed f16 [pos][4]
#define F_FA    2048   // 2048 f32: coset b-slice [pos2=n*4+s][ci]
#define U_MASKB 4096   // 128 u32 = 512 bytes: key mask per pos
#define U_YW1   4224   // 128: pairs (w0,w1) per (ci,j)
#define U_GW1   4352   // 512: pairs [ci][h][4]
#define U_W2Y   4864   // 2048: pairs [ci][row][16]
#define U_W2G   6912   // 2048
#define F_YB1   8960   // 128 f32
#define F_GB1   9088   // 128
#define F_YB2   9216   // 128
#define F_GB2   9344   // 128
#define U_YW3   9472   // 64: pairs [ci][16]
#define U_GW3   9536   // 64
#define F_YB3   9600   // 4
#define F_GB3   9604   // 4
#define F_RED   9608   // 32: [wave][ci][N,D]
#define F_MODE  9640   // 2
#define U_TOTAL 9642   // 38568 B -> 4 blocks/CU still fits (<= 40 KB)

// One block per (bn, s1); 256 threads = 4 waves; wave handles 8 position-
// tiles of 16 (pos = n2*4+s2 in [0,512)).
//
// ALL THREE MLP layers ride the MFMA pipe via one row-permutation trick:
// sigma(4q+r) = 8q+r (tile a) / 8q+4+r (tile b).  An MFMA whose A rows are
// permuted by sigma produces its C output (row = quad*4+reg) exactly in the
// B-fragment layout (row = quad*8+j) of the NEXT layer — zero cross-lane
// fixups anywhere:
//   L1 ky: A = [w0|w1] rows sigma, K=2 padded to 32 (quads 1-3 zero);
//          B word0 = pk(fap, fb).  L1 kg: A = W1g rows sigma, K=8 padded;
//          B = raw packed g vector (garbage k>=8 killed by A=0).
//   L2:    A = W2 rows sigma (full K=32), B = silu(L1 out) packed in-lane.
//   L3:    A row0 = w3 (col==0 lanes only), B = silu(L2 out) packed in-lane;
//          b3 in C row0.  Result a3+b3 lands in quad-0 lanes reg 0 —
//          replaces the 4 serial __shfl_xor of round 1.
// All biases fold into MFMA C operands.  Quads 1-3 compute garbage in the
// tail (zero A rows; e=exp(0) values) — the xor(1,2,4,8) reduce stays inside
// each 16-lane group, and only lane 0 (quad 0) writes, so it never leaks.
// ci loop is unroll-1 with scalar accumulators (runtime-indexed arrays would
// go to scratch), reduced + written to LDS per ci.
// NOTE: MFMA calls guarded by __HIP_DEVICE_COMPILE__ — the host parsing pass
// doesn't know amdgcn builtins.
// [Round 3 = resubmission of round 2: container-level infra failure, no
// kernel verdict. Bounds/alignment/sync re-audited clean.]
__global__ __launch_bounds__(256, 4) void emha_mfma(
    const void* __restrict__ g_pw, const void* __restrict__ g_coset,
    const void* __restrict__ g_mask,
    const void* yW1, const void* yb1, const void* yW2, const void* yb2,
    const void* yW3, const void* yb3,
    const void* gW1, const void* gb1, const void* gW2, const void* gb2,
    const void* gW3, const void* gb3,
    const void* wout, void* outp)
{
    __shared__ __align__(16) unsigned int smu[U_TOTAL];
    float* smf = (float*)smu;
    int*   smi = (int*)smu;
    const int tid = threadIdx.x;

    detect_inline(g_mask, g_coset, tid, smi, F_MODE);
    __syncthreads();
    const int fmode = smi[F_MODE];
    const int mmode = smi[F_MODE + 1];
    __syncthreads();

    const int bn = blockIdx.x >> 2;   // b*128 + n1
    const int s1 = blockIdx.x & 3;
    const int b  = bn >> 7;
    const int n1 = bn & 127;

    // ---- stage pairwise_g slice (pos = n2*4+s2), packed f16 ----
#pragma unroll
    for (int it = 0; it < 2; ++it) {
        const int pos = tid + it * 256;
        const int n2 = pos >> 2, s2 = pos & 3;
        float g8[8];
        load8(g_pw, (((bn * NN + n2) * SS + s1) * SS + s2) * DGG, fmode, g8);
#pragma unroll
        for (int q = 0; q < 4; ++q)
            smu[UG_G + pos * 4 + q] = pk2u(g8[2 * q], g8[2 * q + 1]);
    }
    // ---- stage coset b-slice (f32) and key mask (bytes) ----
    for (int x = tid; x < 2048; x += 256)
        smf[F_FA + x] = loadS(g_coset, b * 2048 + x, fmode);
    {
        unsigned char* mb = (unsigned char*)&smu[U_MASKB];
        for (int x = tid; x < 512; x += 256)
            mb[x] = (unsigned char)load_mask(g_mask, b * 512 + x, mmode);
    }
    // ---- stage all weights packed (f16 pairs) + biases (f32) ----
    stage_pk(&smu[U_YW1], yW1, 128,  fmode, tid);
    stage_pk(&smu[U_GW1], gW1, 512,  fmode, tid);
    stage_pk(&smu[U_W2Y], yW2, 2048, fmode, tid);
    stage_pk(&smu[U_W2G], gW2, 2048, fmode, tid);
    stage_pk(&smu[U_YW3], yW3, 64,   fmode, tid);
    stage_pk(&smu[U_GW3], gW3, 64,   fmode, tid);
    copy_arr(smf, yb1, F_YB1, 128, fmode, tid);
    copy_arr(smf, gb1, F_GB1, 128, fmode, tid);
    copy_arr(smf, yb2, F_YB2, 128, fmode, tid);
    copy_arr(smf, gb2, F_GB2, 128, fmode, tid);
    copy_arr(smf, yb3, F_YB3, 4, fmode, tid);
    copy_arr(smf, gb3, F_GB3, 4, fmode, tid);
    __syncthreads();

    const int lane = tid & 63;
    const int wave = tid >> 6;
    const int quad = lane >> 4;
    const int col  = lane & 15;
    const int qpos = n1 * 4 + s1;                 // query index in b-slice
    const int h0   = ((col >> 2) << 3) + (col & 3);  // sigma row for this lane
    const unsigned char* mb = (const unsigned char*)&smu[U_MASKB];

#pragma unroll 1
    for (int ci = 0; ci < CIN; ++ci) {
        const float fb = smf[F_FA + qpos * 4 + ci];
        const uvec4 zz = {0u, 0u, 0u, 0u};

        // L1 ky A-frags: rows sigma, K=2 (word0 = (w0,w1)), quads 1-3 zero
        const unsigned wy1a = (quad == 0) ? smu[U_YW1 + ci * 32 + h0] : 0u;
        const unsigned wy1b = (quad == 0) ? smu[U_YW1 + ci * 32 + h0 + 4] : 0u;
        const f16x8 AY1a = mk_frag(wy1a, 0u, 0u, 0u);
        const f16x8 AY1b = mk_frag(wy1b, 0u, 0u, 0u);
        const fvec4 cYA = *(const fvec4*)&smf[F_YB1 + ci * 32 + quad * 8];
        const fvec4 cYB = *(const fvec4*)&smf[F_YB1 + ci * 32 + quad * 8 + 4];

        // L1 kg A-frags: W1g rows sigma, K=8, quads 1-3 zero
        uvec4 ga = *(const uvec4*)&smu[U_GW1 + ci * 128 + h0 * 4];
        uvec4 gb = *(const uvec4*)&smu[U_GW1 + ci * 128 + h0 * 4 + 16];
        if (quad != 0) { ga = zz; gb = zz; }
        const f16x8 GA = mk_fragv(ga);
        const f16x8 GB = mk_fragv(gb);
        const fvec4 cGA = *(const fvec4*)&smf[F_GB1 + ci * 32 + quad * 8];
        const fvec4 cGB = *(const fvec4*)&smf[F_GB1 + ci * 32 + quad * 8 + 4];

        // L2 A-frags: W2 rows sigma (full K=32)
        const f16x8 Ay0 = mk_fragv(*(const uvec4*)&smu[U_W2Y + ci * 512 + h0 * 16 + quad * 4]);
        const f16x8 Ay1 = mk_fragv(*(const uvec4*)&smu[U_W2Y + ci * 512 + (h0 + 4) * 16 + quad * 4]);
        const f16x8 Ag0 = mk_fragv(*(const uvec4*)&smu[U_W2G + ci * 512 + h0 * 16 + quad * 4]);
        const f16x8 Ag1 = mk_fragv(*(const uvec4*)&smu[U_W2G + ci * 512 + (h0 + 4) * 16 + quad * 4]);
        const fvec4 cY0 = *(const fvec4*)&smf[F_YB2 + ci * 32 + quad * 8];
        const fvec4 cY1 = *(const fvec4*)&smf[F_YB2 + ci * 32 + quad * 8 + 4];
        const fvec4 cG0 = *(const fvec4*)&smf[F_GB2 + ci * 32 + quad * 8];
        const fvec4 cG1 = *(const fvec4*)&smf[F_GB2 + ci * 32 + quad * 8 + 4];

        // L3 A-frags: row 0 = w3 (col==0 lanes, all quads), b3 in C row 0
        uvec4 a3y = *(const uvec4*)&smu[U_YW3 + ci * 16 + quad * 4];
        uvec4 a3g = *(const uvec4*)&smu[U_GW3 + ci * 16 + quad * 4];
        if (col != 0) { a3y = zz; a3g = zz; }
        const f16x8 A3y = mk_fragv(a3y);
        const f16x8 A3g = mk_fragv(a3g);
        fvec4 C3y = {0.f, 0.f, 0.f, 0.f};
        fvec4 C3g = {0.f, 0.f, 0.f, 0.f};
        if (quad == 0) { C3y[0] = smf[F_YB3 + ci]; C3g[0] = smf[F_GB3 + ci]; }

        float aN = 0.f, aD = 0.f;
#pragma unroll 1
        for (int t = 0; t < 8; ++t) {
            const int pos = (wave * 8 + t) * 16 + col;
            const float fap = smf[F_FA + pos * 4 + ci];
            const int km = mb[pos];
            const uvec4 gq = *(const uvec4*)&smu[UG_G + pos * 4];

            const f16x8 B1y = mk_frag(pk2u(fap, fb), 0u, 0u, 0u);
            const f16x8 Bg1 = mk_fragv(gq);

            f32x4 d1a, d1b, dga, dgb, dy0, dy1, dg0, dg1, dy3, dg3;
#if defined(__HIP_DEVICE_COMPILE__)
            d1a = __builtin_amdgcn_mfma_f32_16x16x32_f16(AY1a, B1y, cYA, 0, 0, 0);
            d1b = __builtin_amdgcn_mfma_f32_16x16x32_f16(AY1b, B1y, cYB, 0, 0, 0);
            dga = __builtin_amdgcn_mfma_f32_16x16x32_f16(GA,   Bg1, cGA, 0, 0, 0);
            dgb = __builtin_amdgcn_mfma_f32_16x16x32_f16(GB,   Bg1, cGB, 0, 0, 0);
#else
            d1a = cYA; d1b = cYB; dga = cGA; dgb = cGB;  // host parse only
#endif
            const f16x8 By = silu_frag(d1a, d1b);
            const f16x8 Bg = silu_frag(dga, dgb);

#if defined(__HIP_DEVICE_COMPILE__)
            dy0 = __builtin_amdgcn_mfma_f32_16x16x32_f16(Ay0, By, cY0, 0, 0, 0);
            dy1 = __builtin_amdgcn_mfma_f32_16x16x32_f16(Ay1, By, cY1, 0, 0, 0);
            dg0 = __builtin_amdgcn_mfma_f32_16x16x32_f16(Ag0, Bg, cG0, 0, 0, 0);
            dg1 = __builtin_amdgcn_mfma_f32_16x16x32_f16(Ag1, Bg, cG1, 0, 0, 0);
#else
            dy0 = cY0; dy1 = cY1; dg0 = cG0; dg1 = cG1;  // host parse only
#endif
            const f16x8 By2 = silu_frag(dy0, dy1);
            const f16x8 Bg2 = silu_frag(dg0, dg1);

#if defined(__HIP_DEVICE_COMPILE__)
            dy3 = __builtin_amdgcn_mfma_f32_16x16x32_f16(A3y, By2, C3y, 0, 0, 0);
            dg3 = __builtin_amdgcn_mfma_f32_16x16x32_f16(A3g, Bg2, C3g, 0, 0, 0);
#else
            dy3 = C3y; dg3 = C3g;  // host parse only
#endif
            // quad-0 lanes hold a3+b3 in reg 0; quads 1-3 compute silu(0)=0
            // garbage that never enters the quad-0 reduce below
            const float kyv = silu_f(dy3[0]);
            const float kgv = silu_f(dg3[0]);
            const float e = km ? exp_f(kyv + kgv) : 0.f;
            aD += e;
            aN += e * fap;
        }
        // reduce over the 16 positions (col bits, inside quad 0)
        aN += __shfl_xor(aN, 1);  aD += __shfl_xor(aD, 1);
        aN += __shfl_xor(aN, 2);  aD += __shfl_xor(aD, 2);
        aN += __shfl_xor(aN, 4);  aD += __shfl_xor(aD, 4);
        aN += __shfl_xor(aN, 8);  aD += __shfl_xor(aD, 8);
        if (lane == 0) {
            smf[F_RED + (wave * 4 + ci) * 2 + 0] = aN;
            smf[F_RED + (wave * 4 + ci) * 2 + 1] = aD;
        }
    }
    __syncthreads();

    if (tid < COUT) {
        const int o = tid;
        const int m1 = mb[qpos];
        float acc = 0.f;
#pragma unroll
        for (int ci = 0; ci < CIN; ++ci) {
            float N = 0.f, D = 0.f;
#pragma unroll
            for (int w = 0; w < 4; ++w) {
                N += smf[F_RED + (w * 4 + ci) * 2 + 0];
                D += smf[F_RED + (w * 4 + ci) * 2 + 1];
            }
            const float fbv = smf[F_FA + qpos * 4 + ci];
            const float cf = m1 ? (fbv + N / D) : 0.f;
            acc += cf * loadS(wout, o * CIN + ci, fmode);
        }
        const int oidx = (bn * SS + s1) * COUT + o;
        if (fmode) ((__hip_bfloat16*)outp)[oidx] = __float2bfloat16(acc);
        else       ((float*)outp)[oidx] = acc;
    }
}

extern "C" void kernel_launch(void* const* d_in, const int* in_sizes, int n_in,
                              void* d_out, int out_size, void* d_ws, size_t ws_size,
                              hipStream_t stream) {
    emha_mfma<<<BB * NN * SS, 256, 0, stream>>>(
        d_in[0], d_in[1], d_in[2],
        d_in[3], d_in[4], d_in[5], d_in[6], d_in[7], d_in[8],
        d_in[9], d_in[10], d_in[11], d_in[12], d_in[13], d_in[14],
        d_in[15], d_out);
}